// Round 19
// baseline (134.982 us; speedup 1.0000x reference)
//
#include <hip/hip_runtime.h>
#include <hip/hip_bf16.h>

#define EPS 1e-5f

__device__ __forceinline__ int reflect_idx(int i, int n) {
    if (i < 0) return -i;
    if (i >= n) return 2 * n - 2 - i;
    return i;
}

// Per-block reduce of 64-slot striped partials -> folded (scale, shift) in LDS.
// Cheap for small grids only (R5 lesson).
__device__ __forceinline__ void block_red(const float* __restrict__ part,
                                          const float* __restrict__ g,
                                          const float* __restrict__ bb,
                                          float* ssl, int C, float invN, int tid) {
    if (tid < C) {
        float s1 = 0.f, s2 = 0.f;
#pragma unroll 8
        for (int s = 0; s < 64; ++s) {
            s1 += part[s * 2 * C + 2 * tid];
            s2 += part[s * 2 * C + 2 * tid + 1];
        }
        float m = s1 * invN;
        float var = s2 * invN - m * m;
        float sc = g[tid] * rsqrtf(var + EPS);
        ssl[2 * tid] = sc;
        ssl[2 * tid + 1] = bb[tid] - m * sc;
    }
}

// Per-wave butterfly reduce of ONE channel's 64-slot partials -> (scale, shift).
__device__ __forceinline__ void wave_red_one(const float* __restrict__ part,
                                             const float* __restrict__ g,
                                             const float* __restrict__ bb,
                                             int C, int o, float invN, int lane,
                                             float& psc, float& psh) {
    float s1 = part[lane * 2 * C + 2 * o];
    float s2 = part[lane * 2 * C + 2 * o + 1];
#pragma unroll
    for (int off = 32; off; off >>= 1) {
        s1 += __shfl_xor(s1, off);
        s2 += __shfl_xor(s2, off);
    }
    float m = s1 * invN;
    float var = s2 * invN - m * m;
    psc = g[o] * rsqrtf(var + EPS);
    psh = bb[o] - m * psc;
}

// ---------------- Fused build + depthwise 3x3 + striped stats (levels 0/1) ----------------
template <int LEVEL, typename OUT_T>
__global__ __launch_bounds__(256)
void fused_dw_kernel(const float* __restrict__ feat, const float* __restrict__ prev,
                     const float* __restrict__ part_prev, const float* __restrict__ g_prev,
                     const float* __restrict__ b_prev, float invN_prev,
                     const float* __restrict__ wsig,
                     OUT_T* __restrict__ out, float* __restrict__ part) {
    constexpr int C    = LEVEL == 0 ? 66 : 98;
    constexpr int H    = LEVEL == 0 ? 32 : 64;
    constexpr int TILE = 16;
    constexpr int NT   = H / TILE;
    constexpr int PXPT = (TILE * TILE) / 256;
    constexpr int WC   = LEVEL == 0 ? 4818 : 4018;
    constexpr int NF   = LEVEL == 0 ? 64 : 32;
    constexpr int Hp   = 32;
    constexpr int Cp   = 64;
    constexpr int P    = H / 8;
    constexpr int HS   = TILE + 2;

    __shared__ float sh[HS * HS];
    int tid = threadIdx.x, bid = blockIdx.x;
    int tile = bid % (NT * NT);
    int c = (bid / (NT * NT)) % C;
    int b = bid / (NT * NT * C);
    int ty0 = (tile / NT) * TILE, tx0 = (tile % NT) * TILE;

    float psc = 0.f, psh = 0.f;
    if constexpr (LEVEL == 1) {
        if (c >= 2 + NF)
            wave_red_one(part_prev, g_prev, b_prev, Cp, c - 2 - NF, invN_prev,
                         tid & 63, psc, psh);
    }

    for (int i = tid; i < HS * HS; i += 256) {
        int h = reflect_idx(ty0 - 1 + i / HS, H);
        int w = reflect_idx(tx0 - 1 + i % HS, H);
        float val;
        if (c == 0)      val = -1.f + 2.f * w / (H - 1);
        else if (c == 1) val = -1.f + 2.f * h / (H - 1);
        else if (c < 2 + NF) val = feat[((size_t)(b * NF + c - 2) * H + h) * H + w];
        else {
            int o = c - 2 - NF;
            const float* pb = prev + (size_t)(b * Cp + o) * Hp * Hp;
            int y0 = (h >> 1) + (h & 1) - 1;
            float fy = (h & 1) ? 0.25f : 0.75f;
            int x0 = (w >> 1) + (w & 1) - 1;
            float fx = (w & 1) ? 0.25f : 0.75f;
            int y0c = max(y0, 0), y1c = min(y0 + 1, Hp - 1);
            int x0c = max(x0, 0), x1c = min(x0 + 1, Hp - 1);
            const float* q0 = pb + y0c * Hp;
            const float* q1 = pb + y1c * Hp;
            float a0 = q0[x0c] + (q0[x1c] - q0[x0c]) * fx;
            float a1 = q1[x0c] + (q1[x1c] - q1[x0c]) * fx;
            float raw = a0 + (a1 - a0) * fy;
            val = raw * psc + psh;
        }
        sh[i] = val;
    }
    __syncthreads();

    float s1 = 0.f, s2 = 0.f;
    OUT_T* ob = out + (((size_t)(b * C + c)) * H + ty0) * H + tx0;
    float wreg[9];
    if constexpr (TILE == P) {
        const float* wb = wsig + ((size_t)(b * WC + c * 9)) * 64 + (ty0 / P) * 8 + (tx0 / P);
#pragma unroll
        for (int t = 0; t < 9; ++t) wreg[t] = wb[(size_t)t * 64];
    }
#pragma unroll
    for (int k = 0; k < PXPT; ++k) {
        int px = tid + k * 256;
        int tyy = px / TILE, txx = px % TILE;
        if constexpr (TILE != P) {
            int u = (ty0 + tyy) / P, vv = (tx0 + txx) / P;
            const float* wb = wsig + ((size_t)(b * WC + c * 9)) * 64 + u * 8 + vv;
#pragma unroll
            for (int t = 0; t < 9; ++t) wreg[t] = wb[(size_t)t * 64];
        }
        float acc = 0.f;
#pragma unroll
        for (int t = 0; t < 9; ++t)
            acc += wreg[t] * sh[(tyy + t / 3) * HS + txx + t % 3];
        if constexpr (sizeof(OUT_T) == 4) ob[tyy * H + txx] = (OUT_T)acc;
        else                              ob[tyy * H + txx] = __float2bfloat16(acc);
        s1 += acc; s2 += acc * acc;
    }
#pragma unroll
    for (int off = 32; off; off >>= 1) {
        s1 += __shfl_xor(s1, off);
        s2 += __shfl_xor(s2, off);
    }
    __shared__ float r1[4], r2[4];
    int wave = tid >> 6;
    if ((tid & 63) == 0) { r1[wave] = s1; r2[wave] = s2; }
    __syncthreads();
    if (tid == 0) {
        int slot = bid & 63;
        atomicAdd(&part[slot * 2 * C + 2 * c],     r1[0] + r1[1] + r1[2] + r1[3]);
        atomicAdd(&part[slot * 2 * C + 2 * c + 1], r2[0] + r2[1] + r2[2] + r2[3]);
    }
}

// ---------------- Level-2 dw: column-per-thread, register-shuffle window, bf16 out ----------
// Built values live in registers (M[10]); L/R come from wave shuffles; only the 8
// wave-boundary columns + 2 reflect columns cross through an 84-float LDS buffer.
__global__ __launch_bounds__(256)
void dw2_col_kernel(const float* __restrict__ ximg, const float* __restrict__ prev,
                    const float* __restrict__ part_pw1, const float* __restrict__ g_pw1,
                    const float* __restrict__ b_pw1,
                    const float* __restrict__ wsig,
                    __hip_bfloat16* __restrict__ out, float* __restrict__ part) {
    const int C = 37, H = 256, W = 256, WC = 1110, Hp = 64, Cp = 32;
    __shared__ float lwv[72];
    __shared__ float bHi[4][10];   // M of lane63 of wave w (column 64w+63)
    __shared__ float bLo[4][10];   // M of lane0 of wave w (column 64w)
    __shared__ float bT0L[10];     // M of column 1  (reflect L for t=0)
    __shared__ float bT255R[10];   // M of column 254 (reflect R for t=255)
    __shared__ float r1[4], r2[4];

    int tid = threadIdx.x, bid = blockIdx.x;
    int rb = bid & 31;
    int c  = (bid >> 5) % C;
    int b  = bid / (32 * C);
    int ty0 = rb * 8;
    int u = rb >> 2;
    int w = tid >> 6, lane = tid & 63;

    float psc = 0.f, psh = 0.f;
    if (c >= 5)
        wave_red_one(part_pw1, g_pw1, b_pw1, Cp, c - 5, 1.f / 16384.f, lane, psc, psh);

    if (tid < 72) {
        int v = tid / 9, t = tid - v * 9;
        lwv[tid] = wsig[((size_t)(b * WC + c * 9 + t)) * 64 + u * 8 + v];
    }

    const float* pb   = (c >= 5) ? prev + (size_t)(b * Cp + (c - 5)) * Hp * Hp : nullptr;
    const float* xrow = (c >= 2 && c < 5) ? ximg + (size_t)(b * 3 + c - 2) * H * W : nullptr;
    int t = tid;
    float cx = -1.f + t * (2.f / 255.f);
    float sxm = (t + 0.5f) * 0.25f - 0.5f;
    int x0m = (int)floorf(sxm);
    float fxm = sxm - x0m;
    int x0cm = min(max(x0m, 0), Hp - 1), x1cm = min(max(x0m + 1, 0), Hp - 1);

    // Build M[r] = built value at (row ty0-1+r, column t), r = 0..9, in registers.
    float M[10];
    if (c >= 5 && rb >= 1 && rb <= 30) {
        int y0b = 2 * rb - 1;
        const float* q0 = pb + (size_t)y0b * Hp;
        const float* q1 = q0 + Hp;
        const float* q2 = q1 + Hp;
        const float* q3 = q2 + Hp;
        float a0 = q0[x0cm] + (q0[x1cm] - q0[x0cm]) * fxm;
        float a1 = q1[x0cm] + (q1[x1cm] - q1[x0cm]) * fxm;
        float a2 = q2[x0cm] + (q2[x1cm] - q2[x0cm]) * fxm;
        float a3 = q3[x0cm] + (q3[x1cm] - q3[x0cm]) * fxm;
        M[0] = (a0 + (a1 - a0) * 0.375f) * psc + psh;
        M[1] = (a0 + (a1 - a0) * 0.625f) * psc + psh;
        M[2] = (a0 + (a1 - a0) * 0.875f) * psc + psh;
        M[3] = (a1 + (a2 - a1) * 0.125f) * psc + psh;
        M[4] = (a1 + (a2 - a1) * 0.375f) * psc + psh;
        M[5] = (a1 + (a2 - a1) * 0.625f) * psc + psh;
        M[6] = (a1 + (a2 - a1) * 0.875f) * psc + psh;
        M[7] = (a2 + (a3 - a2) * 0.125f) * psc + psh;
        M[8] = (a2 + (a3 - a2) * 0.375f) * psc + psh;
        M[9] = (a2 + (a3 - a2) * 0.625f) * psc + psh;
    } else {
#pragma unroll
        for (int r = 0; r < 10; ++r) {
            int h = reflect_idx(ty0 - 1 + r, H);
            float val;
            if (c == 0)      val = cx;
            else if (c == 1) val = -1.f + h * (2.f / 255.f);
            else if (c < 5)  val = xrow[h * W + t];
            else {
                float sy = (h + 0.5f) * 0.25f - 0.5f;
                int y0 = (int)floorf(sy);
                float fy = sy - y0;
                int y0c = min(max(y0, 0), Hp - 1), y1c = min(max(y0 + 1, 0), Hp - 1);
                const float* q0 = pb + y0c * Hp;
                const float* q1 = pb + y1c * Hp;
                float a0 = q0[x0cm] + (q0[x1cm] - q0[x0cm]) * fxm;
                float a1 = q1[x0cm] + (q1[x1cm] - q1[x0cm]) * fxm;
                val = (a0 + (a1 - a0) * fy) * psc + psh;
            }
            M[r] = val;
        }
    }

    // publish boundary columns
#pragma unroll
    for (int r = 0; r < 10; ++r) {
        if (lane == 63) bHi[w][r] = M[r];
        if (lane == 0)  bLo[w][r] = M[r];
        if (t == 1)     bT0L[r]   = M[r];
        if (t == 254)   bT255R[r] = M[r];
    }
    __syncthreads();

    int v = t >> 5;
    float wr[9];
#pragma unroll
    for (int tap = 0; tap < 9; ++tap) wr[tap] = lwv[v * 9 + tap];

    float px[8];
#pragma unroll
    for (int k = 0; k < 8; ++k) px[k] = 0.f;

#pragma unroll
    for (int r = 0; r < 10; ++r) {
        float Mv = M[r];
        float Lv = __shfl_up(Mv, 1);
        if (lane == 0) Lv = (w == 0) ? bT0L[r] : bHi[w - 1][r];
        float Rv = __shfl_down(Mv, 1);
        if (lane == 63) Rv = (w == 3) ? bT255R[r] : bLo[w + 1][r];
#pragma unroll
        for (int dr = 0; dr < 3; ++dr) {
            int k = r - dr;
            if (k >= 0 && k < 8)
                px[k] += wr[dr * 3] * Lv + wr[dr * 3 + 1] * Mv + wr[dr * 3 + 2] * Rv;
        }
    }

    __hip_bfloat16* ob = out + (((size_t)(b * C + c)) * H + ty0) * W + t;
    float s1 = 0.f, s2 = 0.f;
#pragma unroll
    for (int k = 0; k < 8; ++k) {
        ob[k * W] = __float2bfloat16(px[k]);
        s1 += px[k]; s2 += px[k] * px[k];
    }
#pragma unroll
    for (int off = 32; off; off >>= 1) {
        s1 += __shfl_xor(s1, off);
        s2 += __shfl_xor(s2, off);
    }
    if (lane == 0) { r1[w] = s1; r2[w] = s2; }
    __syncthreads();
    if (tid == 0) {
        int slot = bid & 63;
        atomicAdd(&part[slot * 2 * C + 2 * c],     r1[0] + r1[1] + r1[2] + r1[3]);
        atomicAdd(&part[slot * 2 * C + 2 * c + 1], r2[0] + r2[1] + r2[2] + r2[3]);
    }
}

// ---------------- Pointwise 1x1, small levels: fused per-block stats reduce ----------------
template <int C, int ONC, int H, int PX_T, int OC_T, typename IN_T>
__global__ __launch_bounds__(256)
void pw_small_kernel(const IN_T* __restrict__ x, const float* __restrict__ wsig,
                     const float* __restrict__ part_in, const float* __restrict__ g,
                     const float* __restrict__ bb, float invN,
                     float* __restrict__ out, float* __restrict__ part, int WC, int ndw) {
    constexpr int P = H / 8;
    constexpr int OC_I = ONC / OC_T;
    __shared__ float lw[ONC * C];
    __shared__ float lx[C * PX_T];
    __shared__ float ssl[2 * C];
    int tid = threadIdx.x, bid = blockIdx.x;
    int uv = bid & 63, b = bid >> 6;
    int u = uv >> 3, v = uv & 7;

    const size_t wbase = ((size_t)b * WC + ndw) * 64 + uv;
    for (int i = tid; i < ONC * C; i += 256) lw[i] = wsig[wbase + (size_t)i * 64];
    block_red(part_in, g, bb, ssl, C, invN, tid);
    __syncthreads();

    for (int i = tid; i < C * PX_T; i += 256) {
        int c = i / PX_T, pxl = i % PX_T;
        int h = u * P + pxl / P, w = v * P + pxl % P;
        float xv;
        if constexpr (sizeof(IN_T) == 4) xv = x[(((size_t)b * C + c) * H + h) * H + w];
        else xv = __bfloat162float(x[(((size_t)b * C + c) * H + h) * H + w]);
        lx[i] = fminf(fmaxf(xv * ssl[2 * c] + ssl[2 * c + 1], 0.f), 6.f);
    }
    __syncthreads();

    int px_id = tid % PX_T, oc_id = tid / PX_T;
    int h = u * P + px_id / P, w = v * P + px_id % P;
    float acc[OC_I];
#pragma unroll
    for (int oi = 0; oi < OC_I; ++oi) acc[oi] = 0.f;
    for (int c = 0; c < C; ++c) {
        float xv = lx[c * PX_T + px_id];
#pragma unroll
        for (int oi = 0; oi < OC_I; ++oi)
            acc[oi] += lw[(oc_id * OC_I + oi) * C + c] * xv;
    }
    float* ob = out + (((size_t)b * ONC) * H + h) * H + w;
#pragma unroll
    for (int oi = 0; oi < OC_I; ++oi)
        ob[(size_t)(oc_id * OC_I + oi) * H * H] = acc[oi];

    constexpr int GROUP = (PX_T < 64) ? PX_T : 64;
    int lane = tid & 63;
    int slot = bid & 63;
#pragma unroll
    for (int oi = 0; oi < OC_I; ++oi) {
        float s1 = acc[oi], s2 = acc[oi] * acc[oi];
#pragma unroll
        for (int off = GROUP / 2; off; off >>= 1) {
            s1 += __shfl_xor(s1, off);
            s2 += __shfl_xor(s2, off);
        }
        if ((lane & (GROUP - 1)) == 0) {
            int o = oc_id * OC_I + oi;
            atomicAdd(&part[slot * 2 * ONC + 2 * o], s1);
            atomicAdd(&part[slot * 2 * ONC + 2 * o + 1], s2);
        }
    }
}

// ---------------- Pointwise 1x1 level 2: bf16 in/out, fused dw2-stats reduce ----------------
__global__ __launch_bounds__(256)
void pw2_kernel(const __hip_bfloat16* __restrict__ x, const float* __restrict__ wsig,
                const float* __restrict__ part_in, const float* __restrict__ g,
                const float* __restrict__ bb,
                __hip_bfloat16* __restrict__ outb, float* __restrict__ part) {
    const int C = 37, ONC = 21, H = 256, WC = 1110, NDW = 333;
    __shared__ float lw[777];
    __shared__ float ssl[74];
    __shared__ float r1[4][ONC], r2[4][ONC];
    int tid = threadIdx.x, bid = blockIdx.x;
    int chunk = bid & 3;
    int uv = (bid >> 2) & 63;
    int b = bid >> 8;
    int y0 = (uv >> 3) * 32 + chunk * 8, x0 = (uv & 7) * 32;

    for (int i = tid; i < 777; i += 256) lw[i] = wsig[((size_t)(b * WC + NDW) + i) * 64 + uv];
    block_red(part_in, g, bb, ssl, C, 1.f / 262144.f, tid);
    __syncthreads();

    int row = tid >> 5, col = tid & 31;
    const __hip_bfloat16* xb = x + (((size_t)(b * C)) * H + y0 + row) * H + x0 + col;
    float acc[ONC];
#pragma unroll
    for (int o = 0; o < ONC; ++o) acc[o] = 0.f;

    for (int c = 0; c < C; ++c) {
        float xv = __bfloat162float(xb[(size_t)c * H * H]);
        xv = fminf(fmaxf(xv * ssl[2 * c] + ssl[2 * c + 1], 0.f), 6.f);
#pragma unroll
        for (int o = 0; o < ONC; ++o)
            acc[o] += lw[o * C + c] * xv;
    }
    __hip_bfloat16* ob = outb + (((size_t)(b * ONC)) * H + y0 + row) * H + x0 + col;
#pragma unroll
    for (int o = 0; o < ONC; ++o) ob[(size_t)o * H * H] = __float2bfloat16(acc[o]);

    int wave = tid >> 6, lane = tid & 63;
#pragma unroll
    for (int o = 0; o < ONC; ++o) {
        float s1 = acc[o], s2 = acc[o] * acc[o];
#pragma unroll
        for (int off = 32; off; off >>= 1) {
            s1 += __shfl_xor(s1, off);
            s2 += __shfl_xor(s2, off);
        }
        if (lane == 0) { r1[wave][o] = s1; r2[wave][o] = s2; }
    }
    __syncthreads();
    int slot = bid & 63;
    for (int o = tid; o < ONC; o += 256) {
        atomicAdd(&part[slot * 42 + 2 * o],     r1[0][o] + r1[1][o] + r1[2][o] + r1[3][o]);
        atomicAdd(&part[slot * 42 + 2 * o + 1], r2[0][o] + r2[1][o] + r2[2][o] + r2[3][o]);
    }
}

// ---------------- Final BN: fused pw2-stats reduce, bf16 scratch -> fp32 d_out ----------------
__global__ __launch_bounds__(256)
void finalbn_kernel(const __hip_bfloat16* __restrict__ inb, float* __restrict__ out,
                    const float* __restrict__ part_in, const float* __restrict__ g,
                    const float* __restrict__ bb) {
    __shared__ float ssl[42];
    block_red(part_in, g, bb, ssl, 21, 1.f / 262144.f, threadIdx.x);
    __syncthreads();
    const int total4 = 4 * 21 * 256 * 256 / 4;
    for (int idx = blockIdx.x * 256 + threadIdx.x; idx < total4; idx += gridDim.x * 256) {
        int c = (idx / (256 * 256 / 4)) % 21;
        float sc = ssl[2 * c], sb = ssl[2 * c + 1];
        const __hip_bfloat16* ip = inb + (size_t)idx * 4;
        float4 v;
        v.x = __bfloat162float(ip[0]) * sc + sb;
        v.y = __bfloat162float(ip[1]) * sc + sb;
        v.z = __bfloat162float(ip[2]) * sc + sb;
        v.w = __bfloat162float(ip[3]) * sc + sb;
        ((float4*)out)[idx] = v;
    }
}

extern "C" void kernel_launch(void* const* d_in, const int* in_sizes, int n_in,
                              void* d_out, int out_size, void* d_ws, size_t ws_size,
                              hipStream_t stream) {
    const float* x_img = (const float*)d_in[0];
    const float* f0    = (const float*)d_in[1];
    const float* f1    = (const float*)d_in[2];
    const float* w0    = (const float*)d_in[3];
    const float* w1    = (const float*)d_in[4];
    const float* w2    = (const float*)d_in[5];
    const float* g_dw0 = (const float*)d_in[6],  *b_dw0 = (const float*)d_in[7];
    const float* g_pw0 = (const float*)d_in[8],  *b_pw0 = (const float*)d_in[9];
    const float* g_dw1 = (const float*)d_in[10], *b_dw1 = (const float*)d_in[11];
    const float* g_pw1 = (const float*)d_in[12], *b_pw1 = (const float*)d_in[13];
    const float* g_dw2 = (const float*)d_in[14], *b_dw2 = (const float*)d_in[15];
    const float* g_pw2 = (const float*)d_in[16], *b_pw2 = (const float*)d_in[17];
    float* out = (float*)d_out;
    float* ws = (float*)d_ws;

    // workspace layout (floats)
    float* part_dw0 = ws;              // 64*132 = 8448
    float* part_pw0 = ws + 8448;       // 64*128 = 8192
    float* part_dw1 = ws + 16640;      // 64*196 = 12544
    float* part_pw1 = ws + 29184;      // 64*64  = 4096
    float* part_dw2 = ws + 33280;      // 64*74  = 4736
    float* part_pw2 = ws + 38016;      // 64*42  = 2688  -> parts end 40704
    float* pw0raw = ws + 40960;        // 4*64*32*32 = 262144 fp32
    float* pw1raw = pw0raw + 262144;   // 4*32*64*64 = 524288 fp32
    float* bigA   = pw1raw + 524288;   // dw raw region
    __hip_bfloat16* bigAb = (__hip_bfloat16*)bigA;          // L1/L2 dw raw (bf16)
    float* bigA_f32 = bigA;                                  // L0 dw raw (fp32)
    __hip_bfloat16* pw2b = (__hip_bfloat16*)(bigA + 4849664);  // 5505024 bf16

    hipMemsetAsync(ws, 0, 40704 * sizeof(float), stream);

    // ---- Level 0: C=66, 32x32, out 64 ----
    fused_dw_kernel<0, float><<<4 * 66 * 4, 256, 0, stream>>>(
        f1, nullptr, nullptr, nullptr, nullptr, 0.f, w0, bigA_f32, part_dw0);
    pw_small_kernel<66, 64, 32, 16, 16, float><<<256, 256, 0, stream>>>(
        bigA_f32, w0, part_dw0, g_dw0, b_dw0, 1.f / 4096.f, pw0raw, part_pw0, 4818, 594);
    // ---- Level 1: C=98, 64x64, out 32 (bf16 dw intermediate) ----
    fused_dw_kernel<1, __hip_bfloat16><<<4 * 98 * 16, 256, 0, stream>>>(
        f0, pw0raw, part_pw0, g_pw0, b_pw0, 1.f / 4096.f, w1, bigAb, part_dw1);
    pw_small_kernel<98, 32, 64, 64, 4, __hip_bfloat16><<<256, 256, 0, stream>>>(
        bigAb, w1, part_dw1, g_dw1, b_dw1, 1.f / 16384.f, pw1raw, part_pw1, 4018, 882);
    // ---- Level 2: C=37, 256x256, out 21 (bf16 intermediates) ----
    dw2_col_kernel<<<4 * 37 * 32, 256, 0, stream>>>(
        x_img, pw1raw, part_pw1, g_pw1, b_pw1, w2, bigAb, part_dw2);
    pw2_kernel<<<1024, 256, 0, stream>>>(
        bigAb, w2, part_dw2, g_dw2, b_dw2, pw2b, part_pw2);
    finalbn_kernel<<<2048, 256, 0, stream>>>(pw2b, out, part_pw2, g_pw2, b_pw2);
}

// Round 20
// 129.498 us; speedup vs baseline: 1.0423x; 1.0423x over previous
//
#include <hip/hip_runtime.h>
#include <hip/hip_bf16.h>

#define EPS 1e-5f

__device__ __forceinline__ int reflect_idx(int i, int n) {
    if (i < 0) return -i;
    if (i >= n) return 2 * n - 2 - i;
    return i;
}

// Per-block reduce of 64-slot striped partials -> folded (scale, shift) in LDS.
// Cheap for small grids only (R5 lesson).
__device__ __forceinline__ void block_red(const float* __restrict__ part,
                                          const float* __restrict__ g,
                                          const float* __restrict__ bb,
                                          float* ssl, int C, float invN, int tid) {
    if (tid < C) {
        float s1 = 0.f, s2 = 0.f;
#pragma unroll 8
        for (int s = 0; s < 64; ++s) {
            s1 += part[s * 2 * C + 2 * tid];
            s2 += part[s * 2 * C + 2 * tid + 1];
        }
        float m = s1 * invN;
        float var = s2 * invN - m * m;
        float sc = g[tid] * rsqrtf(var + EPS);
        ssl[2 * tid] = sc;
        ssl[2 * tid + 1] = bb[tid] - m * sc;
    }
}

// Per-wave butterfly reduce of ONE channel's 64-slot partials -> (scale, shift).
// 2 loads/lane + 12 shuffles; every lane returns the same value. Big-grid safe.
__device__ __forceinline__ void wave_red_one(const float* __restrict__ part,
                                             const float* __restrict__ g,
                                             const float* __restrict__ bb,
                                             int C, int o, float invN, int lane,
                                             float& psc, float& psh) {
    float s1 = part[lane * 2 * C + 2 * o];
    float s2 = part[lane * 2 * C + 2 * o + 1];
#pragma unroll
    for (int off = 32; off; off >>= 1) {
        s1 += __shfl_xor(s1, off);
        s2 += __shfl_xor(s2, off);
    }
    float m = s1 * invN;
    float var = s2 * invN - m * m;
    psc = g[o] * rsqrtf(var + EPS);
    psh = bb[o] - m * psc;
}

// ---------------- Fused build + depthwise 3x3 + striped stats (levels 0/1) ----------------
// LEVEL 1: inline per-wave BN reduce of the single needed prev-channel (no red_kernel).
template <int LEVEL, typename OUT_T>
__global__ __launch_bounds__(256)
void fused_dw_kernel(const float* __restrict__ feat, const float* __restrict__ prev,
                     const float* __restrict__ part_prev, const float* __restrict__ g_prev,
                     const float* __restrict__ b_prev, float invN_prev,
                     const float* __restrict__ wsig,
                     OUT_T* __restrict__ out, float* __restrict__ part) {
    constexpr int C    = LEVEL == 0 ? 66 : 98;
    constexpr int H    = LEVEL == 0 ? 32 : 64;
    constexpr int TILE = 16;
    constexpr int NT   = H / TILE;
    constexpr int PXPT = (TILE * TILE) / 256;
    constexpr int WC   = LEVEL == 0 ? 4818 : 4018;
    constexpr int NF   = LEVEL == 0 ? 64 : 32;
    constexpr int Hp   = 32;
    constexpr int Cp   = 64;
    constexpr int P    = H / 8;
    constexpr int HS   = TILE + 2;

    __shared__ float sh[HS * HS];
    int tid = threadIdx.x, bid = blockIdx.x;
    int tile = bid % (NT * NT);
    int c = (bid / (NT * NT)) % C;
    int b = bid / (NT * NT * C);
    int ty0 = (tile / NT) * TILE, tx0 = (tile % NT) * TILE;

    float psc = 0.f, psh = 0.f;
    if constexpr (LEVEL == 1) {
        if (c >= 2 + NF)
            wave_red_one(part_prev, g_prev, b_prev, Cp, c - 2 - NF, invN_prev,
                         tid & 63, psc, psh);
    }

    for (int i = tid; i < HS * HS; i += 256) {
        int h = reflect_idx(ty0 - 1 + i / HS, H);
        int w = reflect_idx(tx0 - 1 + i % HS, H);
        float val;
        if (c == 0)      val = -1.f + 2.f * w / (H - 1);
        else if (c == 1) val = -1.f + 2.f * h / (H - 1);
        else if (c < 2 + NF) val = feat[((size_t)(b * NF + c - 2) * H + h) * H + w];
        else {
            int o = c - 2 - NF;
            const float* pb = prev + (size_t)(b * Cp + o) * Hp * Hp;
            int y0 = (h >> 1) + (h & 1) - 1;
            float fy = (h & 1) ? 0.25f : 0.75f;
            int x0 = (w >> 1) + (w & 1) - 1;
            float fx = (w & 1) ? 0.25f : 0.75f;
            int y0c = max(y0, 0), y1c = min(y0 + 1, Hp - 1);
            int x0c = max(x0, 0), x1c = min(x0 + 1, Hp - 1);
            const float* q0 = pb + y0c * Hp;
            const float* q1 = pb + y1c * Hp;
            float a0 = q0[x0c] + (q0[x1c] - q0[x0c]) * fx;
            float a1 = q1[x0c] + (q1[x1c] - q1[x0c]) * fx;
            float raw = a0 + (a1 - a0) * fy;
            val = raw * psc + psh;
        }
        sh[i] = val;
    }
    __syncthreads();

    float s1 = 0.f, s2 = 0.f;
    OUT_T* ob = out + (((size_t)(b * C + c)) * H + ty0) * H + tx0;
    float wreg[9];
    if constexpr (TILE == P) {
        const float* wb = wsig + ((size_t)(b * WC + c * 9)) * 64 + (ty0 / P) * 8 + (tx0 / P);
#pragma unroll
        for (int t = 0; t < 9; ++t) wreg[t] = wb[(size_t)t * 64];
    }
#pragma unroll
    for (int k = 0; k < PXPT; ++k) {
        int px = tid + k * 256;
        int tyy = px / TILE, txx = px % TILE;
        if constexpr (TILE != P) {
            int u = (ty0 + tyy) / P, vv = (tx0 + txx) / P;
            const float* wb = wsig + ((size_t)(b * WC + c * 9)) * 64 + u * 8 + vv;
#pragma unroll
            for (int t = 0; t < 9; ++t) wreg[t] = wb[(size_t)t * 64];
        }
        float acc = 0.f;
#pragma unroll
        for (int t = 0; t < 9; ++t)
            acc += wreg[t] * sh[(tyy + t / 3) * HS + txx + t % 3];
        if constexpr (sizeof(OUT_T) == 4) ob[tyy * H + txx] = (OUT_T)acc;
        else                              ob[tyy * H + txx] = __float2bfloat16(acc);
        s1 += acc; s2 += acc * acc;
    }
#pragma unroll
    for (int off = 32; off; off >>= 1) {
        s1 += __shfl_xor(s1, off);
        s2 += __shfl_xor(s2, off);
    }
    __shared__ float r1[4], r2[4];
    int wave = tid >> 6;
    if ((tid & 63) == 0) { r1[wave] = s1; r2[wave] = s2; }
    __syncthreads();
    if (tid == 0) {
        int slot = bid & 63;
        atomicAdd(&part[slot * 2 * C + 2 * c],     r1[0] + r1[1] + r1[2] + r1[3]);
        atomicAdd(&part[slot * 2 * C + 2 * c + 1], r2[0] + r2[1] + r2[2] + r2[3]);
    }
}

// ---------------- Level-2 dw: column-per-thread, fast row-lerp, bf16 out ----------
// Inline per-wave BN reduce of the single needed pw1 channel (no red_kernel).
__global__ __launch_bounds__(256)
void dw2_col_kernel(const float* __restrict__ ximg, const float* __restrict__ prev,
                    const float* __restrict__ part_pw1, const float* __restrict__ g_pw1,
                    const float* __restrict__ b_pw1,
                    const float* __restrict__ wsig,
                    __hip_bfloat16* __restrict__ out, float* __restrict__ part) {
    const int C = 37, H = 256, W = 256, WC = 1110, Hp = 64, Cp = 32;
    const int S = 260;
    __shared__ float sh[10 * S];
    __shared__ float lwv[72];
    __shared__ float r1[4], r2[4];

    int tid = threadIdx.x, bid = blockIdx.x;
    int rb = bid & 31;
    int c  = (bid >> 5) % C;
    int b  = bid / (32 * C);
    int ty0 = rb * 8;
    int u = rb >> 2;

    float psc = 0.f, psh = 0.f;
    if (c >= 5)
        wave_red_one(part_pw1, g_pw1, b_pw1, Cp, c - 5, 1.f / 16384.f, tid & 63, psc, psh);

    if (tid < 72) {
        int v = tid / 9, t = tid - v * 9;
        lwv[tid] = wsig[((size_t)(b * WC + c * 9 + t)) * 64 + u * 8 + v];
    }
    __syncthreads();

    const float* pb   = (c >= 5) ? prev + (size_t)(b * Cp + (c - 5)) * Hp * Hp : nullptr;
    const float* xrow = (c >= 2 && c < 5) ? ximg + (size_t)(b * 3 + c - 2) * H * W : nullptr;
    float cx = -1.f + tid * (2.f / 255.f);
    float sxm = (tid + 0.5f) * 0.25f - 0.5f;
    int x0m = (int)floorf(sxm);
    float fxm = sxm - x0m;
    int x0cm = min(max(x0m, 0), Hp - 1), x1cm = min(max(x0m + 1, 0), Hp - 1);

    if (c >= 5 && rb >= 1 && rb <= 30) {
        int y0b = 2 * rb - 1;
        const float* q0 = pb + (size_t)y0b * Hp;
        const float* q1 = q0 + Hp;
        const float* q2 = q1 + Hp;
        const float* q3 = q2 + Hp;
        float a0 = q0[x0cm] + (q0[x1cm] - q0[x0cm]) * fxm;
        float a1 = q1[x0cm] + (q1[x1cm] - q1[x0cm]) * fxm;
        float a2 = q2[x0cm] + (q2[x1cm] - q2[x0cm]) * fxm;
        float a3 = q3[x0cm] + (q3[x1cm] - q3[x0cm]) * fxm;
        sh[0 * S + tid + 1] = (a0 + (a1 - a0) * 0.375f) * psc + psh;
        sh[1 * S + tid + 1] = (a0 + (a1 - a0) * 0.625f) * psc + psh;
        sh[2 * S + tid + 1] = (a0 + (a1 - a0) * 0.875f) * psc + psh;
        sh[3 * S + tid + 1] = (a1 + (a2 - a1) * 0.125f) * psc + psh;
        sh[4 * S + tid + 1] = (a1 + (a2 - a1) * 0.375f) * psc + psh;
        sh[5 * S + tid + 1] = (a1 + (a2 - a1) * 0.625f) * psc + psh;
        sh[6 * S + tid + 1] = (a1 + (a2 - a1) * 0.875f) * psc + psh;
        sh[7 * S + tid + 1] = (a2 + (a3 - a2) * 0.125f) * psc + psh;
        sh[8 * S + tid + 1] = (a2 + (a3 - a2) * 0.375f) * psc + psh;
        sh[9 * S + tid + 1] = (a2 + (a3 - a2) * 0.625f) * psc + psh;
    } else {
#pragma unroll
        for (int r = 0; r < 10; ++r) {
            int h = reflect_idx(ty0 - 1 + r, H);
            float val;
            if (c == 0)      val = cx;
            else if (c == 1) val = -1.f + h * (2.f / 255.f);
            else if (c < 5)  val = xrow[h * W + tid];
            else {
                float sy = (h + 0.5f) * 0.25f - 0.5f;
                int y0 = (int)floorf(sy);
                float fy = sy - y0;
                int y0c = min(max(y0, 0), Hp - 1), y1c = min(max(y0 + 1, 0), Hp - 1);
                const float* q0 = pb + y0c * Hp;
                const float* q1 = pb + y1c * Hp;
                float a0 = q0[x0cm] + (q0[x1cm] - q0[x0cm]) * fxm;
                float a1 = q1[x0cm] + (q1[x1cm] - q1[x0cm]) * fxm;
                val = (a0 + (a1 - a0) * fy) * psc + psh;
            }
            sh[r * S + tid + 1] = val;
        }
    }
    if (tid < 20) {
        int r = tid >> 1, side = tid & 1;
        int wimg = side ? 254 : 1;               // reflect(-1)=1, reflect(256)=254
        int h = reflect_idx(ty0 - 1 + r, H);
        float val;
        if (c == 0)      val = -1.f + wimg * (2.f / 255.f);
        else if (c == 1) val = -1.f + h * (2.f / 255.f);
        else if (c < 5)  val = xrow[h * W + wimg];
        else {
            float sx = (wimg + 0.5f) * 0.25f - 0.5f;
            int x0 = (int)floorf(sx); float fx = sx - x0;
            int x0c = min(max(x0, 0), Hp - 1), x1c = min(max(x0 + 1, 0), Hp - 1);
            float sy = (h + 0.5f) * 0.25f - 0.5f;
            int y0 = (int)floorf(sy); float fy = sy - y0;
            int y0c = min(max(y0, 0), Hp - 1), y1c = min(max(y0 + 1, 0), Hp - 1);
            const float* q0 = pb + y0c * Hp;
            const float* q1 = pb + y1c * Hp;
            float a0 = q0[x0c] + (q0[x1c] - q0[x0c]) * fx;
            float a1 = q1[x0c] + (q1[x1c] - q1[x0c]) * fx;
            val = (a0 + (a1 - a0) * fy) * psc + psh;
        }
        sh[r * S + (side ? 257 : 0)] = val;
    }
    __syncthreads();

    int t = tid;
    int v = t >> 5;
    float wr[9];
#pragma unroll
    for (int tap = 0; tap < 9; ++tap) wr[tap] = lwv[v * 9 + tap];

    float px[8];
#pragma unroll
    for (int k = 0; k < 8; ++k) px[k] = 0.f;

#pragma unroll
    for (int r = 0; r < 10; ++r) {
        float L = sh[r * S + t];
        float M = sh[r * S + t + 1];
        float R = sh[r * S + t + 2];
#pragma unroll
        for (int dr = 0; dr < 3; ++dr) {
            int k = r - dr;
            if (k >= 0 && k < 8)
                px[k] += wr[dr * 3] * L + wr[dr * 3 + 1] * M + wr[dr * 3 + 2] * R;
        }
    }

    __hip_bfloat16* ob = out + (((size_t)(b * C + c)) * H + ty0) * W + t;
    float s1 = 0.f, s2 = 0.f;
#pragma unroll
    for (int k = 0; k < 8; ++k) {
        ob[k * W] = __float2bfloat16(px[k]);
        s1 += px[k]; s2 += px[k] * px[k];
    }
#pragma unroll
    for (int off = 32; off; off >>= 1) {
        s1 += __shfl_xor(s1, off);
        s2 += __shfl_xor(s2, off);
    }
    int wave = tid >> 6;
    if ((tid & 63) == 0) { r1[wave] = s1; r2[wave] = s2; }
    __syncthreads();
    if (tid == 0) {
        int slot = bid & 63;
        atomicAdd(&part[slot * 2 * C + 2 * c],     r1[0] + r1[1] + r1[2] + r1[3]);
        atomicAdd(&part[slot * 2 * C + 2 * c + 1], r2[0] + r2[1] + r2[2] + r2[3]);
    }
}

// ---------------- Pointwise 1x1, small levels: fused per-block stats reduce ----------------
template <int C, int ONC, int H, int PX_T, int OC_T, typename IN_T>
__global__ __launch_bounds__(256)
void pw_small_kernel(const IN_T* __restrict__ x, const float* __restrict__ wsig,
                     const float* __restrict__ part_in, const float* __restrict__ g,
                     const float* __restrict__ bb, float invN,
                     float* __restrict__ out, float* __restrict__ part, int WC, int ndw) {
    constexpr int P = H / 8;
    constexpr int OC_I = ONC / OC_T;
    __shared__ float lw[ONC * C];
    __shared__ float lx[C * PX_T];
    __shared__ float ssl[2 * C];
    int tid = threadIdx.x, bid = blockIdx.x;
    int uv = bid & 63, b = bid >> 6;
    int u = uv >> 3, v = uv & 7;

    const size_t wbase = ((size_t)b * WC + ndw) * 64 + uv;
    for (int i = tid; i < ONC * C; i += 256) lw[i] = wsig[wbase + (size_t)i * 64];
    block_red(part_in, g, bb, ssl, C, invN, tid);
    __syncthreads();

    for (int i = tid; i < C * PX_T; i += 256) {
        int c = i / PX_T, pxl = i % PX_T;
        int h = u * P + pxl / P, w = v * P + pxl % P;
        float xv;
        if constexpr (sizeof(IN_T) == 4) xv = x[(((size_t)b * C + c) * H + h) * H + w];
        else xv = __bfloat162float(x[(((size_t)b * C + c) * H + h) * H + w]);
        lx[i] = fminf(fmaxf(xv * ssl[2 * c] + ssl[2 * c + 1], 0.f), 6.f);
    }
    __syncthreads();

    int px_id = tid % PX_T, oc_id = tid / PX_T;
    int h = u * P + px_id / P, w = v * P + px_id % P;
    float acc[OC_I];
#pragma unroll
    for (int oi = 0; oi < OC_I; ++oi) acc[oi] = 0.f;
    for (int c = 0; c < C; ++c) {
        float xv = lx[c * PX_T + px_id];
#pragma unroll
        for (int oi = 0; oi < OC_I; ++oi)
            acc[oi] += lw[(oc_id * OC_I + oi) * C + c] * xv;
    }
    float* ob = out + (((size_t)b * ONC) * H + h) * H + w;
#pragma unroll
    for (int oi = 0; oi < OC_I; ++oi)
        ob[(size_t)(oc_id * OC_I + oi) * H * H] = acc[oi];

    constexpr int GROUP = (PX_T < 64) ? PX_T : 64;
    int lane = tid & 63;
    int slot = bid & 63;
#pragma unroll
    for (int oi = 0; oi < OC_I; ++oi) {
        float s1 = acc[oi], s2 = acc[oi] * acc[oi];
#pragma unroll
        for (int off = GROUP / 2; off; off >>= 1) {
            s1 += __shfl_xor(s1, off);
            s2 += __shfl_xor(s2, off);
        }
        if ((lane & (GROUP - 1)) == 0) {
            int o = oc_id * OC_I + oi;
            atomicAdd(&part[slot * 2 * ONC + 2 * o], s1);
            atomicAdd(&part[slot * 2 * ONC + 2 * o + 1], s2);
        }
    }
}

// ---------------- Pointwise 1x1 level 2: bf16 in/out, fused dw2-stats reduce ----------------
__global__ __launch_bounds__(256)
void pw2_kernel(const __hip_bfloat16* __restrict__ x, const float* __restrict__ wsig,
                const float* __restrict__ part_in, const float* __restrict__ g,
                const float* __restrict__ bb,
                __hip_bfloat16* __restrict__ outb, float* __restrict__ part) {
    const int C = 37, ONC = 21, H = 256, WC = 1110, NDW = 333;
    __shared__ float lw[777];
    __shared__ float ssl[74];
    __shared__ float r1[4][ONC], r2[4][ONC];
    int tid = threadIdx.x, bid = blockIdx.x;
    int chunk = bid & 3;
    int uv = (bid >> 2) & 63;
    int b = bid >> 8;
    int y0 = (uv >> 3) * 32 + chunk * 8, x0 = (uv & 7) * 32;

    for (int i = tid; i < 777; i += 256) lw[i] = wsig[((size_t)(b * WC + NDW) + i) * 64 + uv];
    block_red(part_in, g, bb, ssl, C, 1.f / 262144.f, tid);
    __syncthreads();

    int row = tid >> 5, col = tid & 31;
    const __hip_bfloat16* xb = x + (((size_t)(b * C)) * H + y0 + row) * H + x0 + col;
    float acc[ONC];
#pragma unroll
    for (int o = 0; o < ONC; ++o) acc[o] = 0.f;

    for (int c = 0; c < C; ++c) {
        float xv = __bfloat162float(xb[(size_t)c * H * H]);
        xv = fminf(fmaxf(xv * ssl[2 * c] + ssl[2 * c + 1], 0.f), 6.f);
#pragma unroll
        for (int o = 0; o < ONC; ++o)
            acc[o] += lw[o * C + c] * xv;
    }
    __hip_bfloat16* ob = outb + (((size_t)(b * ONC)) * H + y0 + row) * H + x0 + col;
#pragma unroll
    for (int o = 0; o < ONC; ++o) ob[(size_t)o * H * H] = __float2bfloat16(acc[o]);

    int wave = tid >> 6, lane = tid & 63;
#pragma unroll
    for (int o = 0; o < ONC; ++o) {
        float s1 = acc[o], s2 = acc[o] * acc[o];
#pragma unroll
        for (int off = 32; off; off >>= 1) {
            s1 += __shfl_xor(s1, off);
            s2 += __shfl_xor(s2, off);
        }
        if (lane == 0) { r1[wave][o] = s1; r2[wave][o] = s2; }
    }
    __syncthreads();
    int slot = bid & 63;
    for (int o = tid; o < ONC; o += 256) {
        atomicAdd(&part[slot * 42 + 2 * o],     r1[0][o] + r1[1][o] + r1[2][o] + r1[3][o]);
        atomicAdd(&part[slot * 42 + 2 * o + 1], r2[0][o] + r2[1][o] + r2[2][o] + r2[3][o]);
    }
}

// ---------------- Final BN: fused pw2-stats reduce, bf16 scratch -> fp32 d_out ----------------
__global__ __launch_bounds__(256)
void finalbn_kernel(const __hip_bfloat16* __restrict__ inb, float* __restrict__ out,
                    const float* __restrict__ part_in, const float* __restrict__ g,
                    const float* __restrict__ bb) {
    __shared__ float ssl[42];
    block_red(part_in, g, bb, ssl, 21, 1.f / 262144.f, threadIdx.x);
    __syncthreads();
    const int total4 = 4 * 21 * 256 * 256 / 4;
    for (int idx = blockIdx.x * 256 + threadIdx.x; idx < total4; idx += gridDim.x * 256) {
        int c = (idx / (256 * 256 / 4)) % 21;
        float sc = ssl[2 * c], sb = ssl[2 * c + 1];
        const __hip_bfloat16* ip = inb + (size_t)idx * 4;
        float4 v;
        v.x = __bfloat162float(ip[0]) * sc + sb;
        v.y = __bfloat162float(ip[1]) * sc + sb;
        v.z = __bfloat162float(ip[2]) * sc + sb;
        v.w = __bfloat162float(ip[3]) * sc + sb;
        ((float4*)out)[idx] = v;
    }
}

extern "C" void kernel_launch(void* const* d_in, const int* in_sizes, int n_in,
                              void* d_out, int out_size, void* d_ws, size_t ws_size,
                              hipStream_t stream) {
    const float* x_img = (const float*)d_in[0];
    const float* f0    = (const float*)d_in[1];
    const float* f1    = (const float*)d_in[2];
    const float* w0    = (const float*)d_in[3];
    const float* w1    = (const float*)d_in[4];
    const float* w2    = (const float*)d_in[5];
    const float* g_dw0 = (const float*)d_in[6],  *b_dw0 = (const float*)d_in[7];
    const float* g_pw0 = (const float*)d_in[8],  *b_pw0 = (const float*)d_in[9];
    const float* g_dw1 = (const float*)d_in[10], *b_dw1 = (const float*)d_in[11];
    const float* g_pw1 = (const float*)d_in[12], *b_pw1 = (const float*)d_in[13];
    const float* g_dw2 = (const float*)d_in[14], *b_dw2 = (const float*)d_in[15];
    const float* g_pw2 = (const float*)d_in[16], *b_pw2 = (const float*)d_in[17];
    float* out = (float*)d_out;
    float* ws = (float*)d_ws;

    // workspace layout (floats)
    float* part_dw0 = ws;              // 64*132 = 8448
    float* part_pw0 = ws + 8448;       // 64*128 = 8192
    float* part_dw1 = ws + 16640;      // 64*196 = 12544
    float* part_pw1 = ws + 29184;      // 64*64  = 4096
    float* part_dw2 = ws + 33280;      // 64*74  = 4736
    float* part_pw2 = ws + 38016;      // 64*42  = 2688  -> parts end 40704
    float* pw0raw = ws + 40960;        // 4*64*32*32 = 262144 fp32
    float* pw1raw = pw0raw + 262144;   // 4*32*64*64 = 524288 fp32
    float* bigA   = pw1raw + 524288;   // dw raw region
    __hip_bfloat16* bigAb = (__hip_bfloat16*)bigA;          // L1/L2 dw raw (bf16)
    float* bigA_f32 = bigA;                                  // L0 dw raw (fp32)
    __hip_bfloat16* pw2b = (__hip_bfloat16*)(bigA + 4849664);  // 5505024 bf16

    hipMemsetAsync(ws, 0, 40704 * sizeof(float), stream);

    // ---- Level 0: C=66, 32x32, out 64 ----
    fused_dw_kernel<0, float><<<4 * 66 * 4, 256, 0, stream>>>(
        f1, nullptr, nullptr, nullptr, nullptr, 0.f, w0, bigA_f32, part_dw0);
    pw_small_kernel<66, 64, 32, 16, 16, float><<<256, 256, 0, stream>>>(
        bigA_f32, w0, part_dw0, g_dw0, b_dw0, 1.f / 4096.f, pw0raw, part_pw0, 4818, 594);
    // ---- Level 1: C=98, 64x64, out 32 (bf16 dw intermediate) ----
    fused_dw_kernel<1, __hip_bfloat16><<<4 * 98 * 16, 256, 0, stream>>>(
        f0, pw0raw, part_pw0, g_pw0, b_pw0, 1.f / 4096.f, w1, bigAb, part_dw1);
    pw_small_kernel<98, 32, 64, 64, 4, __hip_bfloat16><<<256, 256, 0, stream>>>(
        bigAb, w1, part_dw1, g_dw1, b_dw1, 1.f / 16384.f, pw1raw, part_pw1, 4018, 882);
    // ---- Level 2: C=37, 256x256, out 21 (bf16 intermediates) ----
    dw2_col_kernel<<<4 * 37 * 32, 256, 0, stream>>>(
        x_img, pw1raw, part_pw1, g_pw1, b_pw1, w2, bigAb, part_dw2);
    pw2_kernel<<<1024, 256, 0, stream>>>(
        bigAb, w2, part_dw2, g_dw2, b_dw2, pw2b, part_pw2);
    finalbn_kernel<<<2048, 256, 0, stream>>>(pw2b, out, part_pw2, g_pw2, b_pw2);
}